// Round 9
// baseline (662.249 us; speedup 1.0000x reference)
//
#include <hip/hip_runtime.h>
#include <hip/hip_bf16.h>
#include <hip/hip_cooperative_groups.h>
#include <math.h>

namespace cg = cooperative_groups;

// GAT forward, N=4096, F=512, H=8, NH=64.
// Round 9: single cooperative mega-kernel (512 blocks x 512 threads) with
// grid.sync() between the 5 phases; r6 math verbatim. Fallback to the r6
// 5-kernel sequence if cooperative launch is unavailable.

#define GN 4096
#define GF 512

typedef __attribute__((ext_vector_type(8))) short bf16x8;
typedef __attribute__((ext_vector_type(4))) float f32x4;

__device__ inline unsigned short f2bf(float f) {
    unsigned u = __float_as_uint(f);
    return (unsigned short)((u + 0x7fffu + ((u >> 16) & 1u)) >> 16);
}
__device__ inline float bf2f(unsigned short h) {
    return __uint_as_float((unsigned)h << 16);
}
__device__ inline void split2(float v, unsigned short& h, unsigned short& l) {
    h = f2bf(v);
    l = f2bf(v - bf2f(h));
}
__device__ inline void gl16(const void* g, void* l) {
    __builtin_amdgcn_global_load_lds((const __attribute__((address_space(1))) unsigned int*)g,
                                     (__attribute__((address_space(3))) unsigned int*)l, 16, 0, 0);
}

struct GArgs {
    const float *adj, *Ws, *Wo, *x, *a1, *a2, *ao1, *ao2;
    float *out, *Wh, *Who, *sbuf, *dbuf, *spart, *dpart;
    unsigned short *nbrs;
    int *deg;
    unsigned short *xhi, *xlo, *hch, *hcl, *wshi, *wslo, *wohi, *wolo;
};

// ---- gemm phase: C = A@B, 64x64 tile, 512 thr, 8 waves (4m x 2n of 16x32),
// BK=64 dbuf 2x32KB, 3-term bf16 split, both-sides XOR swizzle.
template<bool PART>
__device__ void gemm_phase(const unsigned short* __restrict__ Ahi,
                           const unsigned short* __restrict__ Alo,
                           const unsigned short* __restrict__ Bhi,
                           const unsigned short* __restrict__ Blo,
                           const float* __restrict__ a1v, const float* __restrict__ a2v,
                           float* __restrict__ C, float* __restrict__ sdst,
                           float* __restrict__ ddst, char* LDSU, int blk, int t) {
    constexpr int K = 512, Nc = 512, Mrows = GN;
    const int lane = t & 63, wid = t >> 6;
    const int bn0 = (blk & 7) * 64, bm0 = (blk >> 3) * 64;
    const int r0 = t >> 3;
    const int sc8 = (((t & 7) ^ (r0 & 7)) << 3);
    const size_t aoff = (size_t)(bm0 + r0) * K + sc8;
    const size_t boff = (size_t)(bn0 + r0) * K + sc8;

    auto stage = [&](char* dst, int k0) {
        gl16(Ahi + aoff + k0, dst + 0 * 8192 + t * 16);
        gl16(Alo + aoff + k0, dst + 1 * 8192 + t * 16);
        gl16(Bhi + boff + k0, dst + 2 * 8192 + t * 16);
        gl16(Blo + boff + k0, dst + 3 * 8192 + t * 16);
    };

    f32x4 acc0 = {0,0,0,0}, acc1 = {0,0,0,0};
    const int wr = wid >> 1, wc = wid & 1;
    const int rl = lane & 15, hl = lane >> 4, swz = rl & 7;

    auto compute = [&](const char* Lb) {
        #pragma unroll
        for (int s = 0; s < 2; ++s) {
            const int ch = ((s * 4 + hl) ^ swz) * 16;
            const int ra  = (wr * 16 + rl) * 128;
            const int rb0 = (wc * 32 + rl) * 128, rb1 = rb0 + 2048;
            bf16x8 Ah = *(const bf16x8*)(Lb + ra + ch);
            bf16x8 Al = *(const bf16x8*)(Lb + 8192 + ra + ch);
            bf16x8 B0h = *(const bf16x8*)(Lb + 16384 + rb0 + ch);
            bf16x8 B1h = *(const bf16x8*)(Lb + 16384 + rb1 + ch);
            bf16x8 B0l = *(const bf16x8*)(Lb + 24576 + rb0 + ch);
            bf16x8 B1l = *(const bf16x8*)(Lb + 24576 + rb1 + ch);
            acc0 = __builtin_amdgcn_mfma_f32_16x16x32_bf16(Ah, B0h, acc0, 0, 0, 0);
            acc1 = __builtin_amdgcn_mfma_f32_16x16x32_bf16(Ah, B1h, acc1, 0, 0, 0);
            acc0 = __builtin_amdgcn_mfma_f32_16x16x32_bf16(Ah, B0l, acc0, 0, 0, 0);
            acc1 = __builtin_amdgcn_mfma_f32_16x16x32_bf16(Ah, B1l, acc1, 0, 0, 0);
            acc0 = __builtin_amdgcn_mfma_f32_16x16x32_bf16(Al, B0h, acc0, 0, 0, 0);
            acc1 = __builtin_amdgcn_mfma_f32_16x16x32_bf16(Al, B1h, acc1, 0, 0, 0);
        }
    };

    stage(LDSU, 0);
    __syncthreads();
    for (int st = 0; st < 8; ++st) {
        char* cur = LDSU + (st & 1) * 32768;
        if (st < 7) stage(LDSU + ((st + 1) & 1) * 32768, (st + 1) * 64);
        compute(cur);
        __syncthreads();
    }

    #pragma unroll
    for (int j = 0; j < 4; ++j) {
        const size_t row = bm0 + wr * 16 + hl * 4 + j;
        C[row * Nc + bn0 + wc * 32 + rl]      = acc0[j];
        C[row * Nc + bn0 + wc * 32 + 16 + rl] = acc1[j];
    }

    // fused s/d epilogue (exact f32)
    const int c0 = bn0 + wc * 32 + rl, c1 = c0 + 16;
    const float a1c0 = a1v[c0], a1c1 = a1v[c1];
    const float a2c0 = a2v[c0], a2c1 = a2v[c1];
    float ps[4], pd[4];
    #pragma unroll
    for (int j = 0; j < 4; ++j) {
        ps[j] = acc0[j] * a1c0 + acc1[j] * a1c1;
        pd[j] = acc0[j] * a2c0 + acc1[j] * a2c1;
    }
    #pragma unroll
    for (int off = 1; off < 16; off <<= 1) {
        #pragma unroll
        for (int j = 0; j < 4; ++j) {
            ps[j] += __shfl_xor(ps[j], off);
            pd[j] += __shfl_xor(pd[j], off);
        }
    }
    float* eps = (float*)LDSU;            // [0:128) s(row,wc), [128:256) d
    if (rl == 0) {
        #pragma unroll
        for (int j = 0; j < 4; ++j) {
            const int rr = wr * 16 + hl * 4 + j;
            eps[rr * 2 + wc]       = ps[j];
            eps[128 + rr * 2 + wc] = pd[j];
        }
    }
    __syncthreads();
    if (t < 64) {
        const float sv = eps[t * 2] + eps[t * 2 + 1];
        const float dv = eps[128 + t * 2] + eps[128 + t * 2 + 1];
        if constexpr (PART) {
            sdst[(size_t)(bm0 + t) * 8 + (blk & 7)] = sv;
            ddst[(size_t)(bm0 + t) * 8 + (blk & 7)] = dv;
        } else {
            sdst[(size_t)(blk & 7) * Mrows + bm0 + t] = sv;
            ddst[(size_t)(blk & 7) * Mrows + bm0 + t] = dv;
        }
    }
    __syncthreads();
}

// ---- attn phase: one 256-thread half handles one row (two rows per block).
template<int H, bool SPLIT, bool PART8>
__device__ void attn_one(char* LDSU, int t, int row,
        const float* __restrict__ W, const float* __restrict__ s,
        const float* __restrict__ d, const unsigned short* __restrict__ nbr,
        const int* __restrict__ deg, float* __restrict__ outp,
        unsigned short* __restrict__ ohi, unsigned short* __restrict__ olo) {
    constexpr int F = 512, NH = F / H, GS = 256 / H;
    const int half = t >> 8, sub = t & 255;
    char* hb = LDSU + half * 20480;
    int*   nb   = (int*)hb;                     // 512 ints
    float* p    = (float*)(hb + 2048);          // [H][512]
    float* lred = (float*)(hb + 18560);         // H floats
    float* red  = (float*)(hb + 18624);         // 4 floats
    const int M = deg[row];
    for (int j = sub; j < M; j += 256) nb[j] = nbr[(size_t)row * 512 + j];
    __syncthreads();
    const int h = sub / GS, gsub = sub % GS;
    float sh;
    if constexpr (PART8) {
        const float4* sp = (const float4*)(s + (size_t)row * 8);
        float4 s0 = sp[0], s1 = sp[1];
        sh = ((s0.x + s0.y) + (s0.z + s0.w)) + ((s1.x + s1.y) + (s1.z + s1.w));
    } else {
        sh = s[h * GN + row];
    }
    float lm = -INFINITY;
    for (int j = gsub; j < M; j += GS) {
        float dv;
        if constexpr (PART8) {
            const float4* dp = (const float4*)(d + (size_t)nb[j] * 8);
            float4 d0 = dp[0], d1 = dp[1];
            dv = ((d0.x + d0.y) + (d0.z + d0.w)) + ((d1.x + d1.y) + (d1.z + d1.w));
        } else {
            dv = d[h * GN + nb[j]];
        }
        float e = sh + dv;
        e = e > 0.f ? e : 0.2f * e;
        p[h * 512 + j] = e;
        lm = fmaxf(lm, e);
    }
    if constexpr (GS <= 64) {
        #pragma unroll
        for (int off = GS / 2; off; off >>= 1) lm = fmaxf(lm, __shfl_xor(lm, off));
    } else {
        #pragma unroll
        for (int off = 32; off; off >>= 1) lm = fmaxf(lm, __shfl_xor(lm, off));
        if ((sub & 63) == 0) red[sub >> 6] = lm;
        __syncthreads();
        lm = fmaxf(fmaxf(red[0], red[1]), fmaxf(red[2], red[3]));
    }
    float ls = 0.f;
    for (int j = gsub; j < M; j += GS) {
        float pe = expf(p[h * 512 + j] - lm);
        p[h * 512 + j] = pe;
        ls += pe;
    }
    if constexpr (GS <= 64) {
        #pragma unroll
        for (int off = GS / 2; off; off >>= 1) ls += __shfl_xor(ls, off);
    } else {
        #pragma unroll
        for (int off = 32; off; off >>= 1) ls += __shfl_xor(ls, off);
        __syncthreads();
        if ((sub & 63) == 0) red[sub >> 6] = ls;
        __syncthreads();
        ls = red[0] + red[1] + red[2] + red[3];
    }
    if (gsub == 0) lred[h] = ls;
    __syncthreads();
    const int c = 2 * sub;
    const int hc = c / NH;
    const float inv = 1.f / lred[hc];
    const float* basep = W + c;
    float ax = 0.f, ay = 0.f;
    #pragma unroll 4
    for (int j = 0; j < M; ++j) {
        float pw = p[hc * 512 + j];
        const float2 w = *(const float2*)(basep + (size_t)nb[j] * F);
        ax += pw * w.x; ay += pw * w.y;
    }
    ax *= inv; ay *= inv;
    ax = ax > 0.f ? ax : expm1f(ax);
    ay = ay > 0.f ? ay : expm1f(ay);
    if constexpr (SPLIT) {
        unsigned short hx, lx, hy, ly;
        split2(ax, hx, lx); split2(ay, hy, ly);
        ushort2 hv, lv;
        hv.x = hx; hv.y = hy; lv.x = lx; lv.y = ly;
        *(ushort2*)(ohi + (size_t)row * F + c) = hv;
        *(ushort2*)(olo + (size_t)row * F + c) = lv;
    } else {
        float2 o; o.x = ax; o.y = ay;
        *(float2*)(outp + (size_t)row * F + c) = o;
    }
    __syncthreads();                      // LDS reuse across row iterations
}

__global__ __launch_bounds__(512, 4) void gat_mega(GArgs a) {
    __shared__ __align__(16) char LDSU[65536];
    const int t = threadIdx.x, blk = blockIdx.x;
    const int lane = t & 63, wid = t >> 6;
    cg::grid_group grid = cg::this_grid();

    // ---- P0: prep ----
    {   // neighbor extraction: 8 rows per block, 512 threads per row
        int* wtot  = (int*)LDSU;
        int* wbase = wtot + 8;
        for (int it = 0; it < 8; ++it) {
            const int row = blk * 8 + it;
            const float4* arow = (const float4*)(a.adj + (size_t)row * GN);
            float4 v0 = arow[t * 2], v1 = arow[t * 2 + 1];
            unsigned m8 = 0;
            if (v0.x > 0.f) m8 |= 1u;   if (v0.y > 0.f) m8 |= 2u;
            if (v0.z > 0.f) m8 |= 4u;   if (v0.w > 0.f) m8 |= 8u;
            if (v1.x > 0.f) m8 |= 16u;  if (v1.y > 0.f) m8 |= 32u;
            if (v1.z > 0.f) m8 |= 64u;  if (v1.w > 0.f) m8 |= 128u;
            int cnt = __popc(m8);
            int inc = cnt;
            #pragma unroll
            for (int off = 1; off < 64; off <<= 1) {
                int nv = __shfl_up(inc, off);
                if (lane >= off) inc += nv;
            }
            if (lane == 63) wtot[wid] = inc;
            __syncthreads();
            if (t == 0) {
                int ssum = 0;
                #pragma unroll
                for (int w = 0; w < 8; ++w) { wbase[w] = ssum; ssum += wtot[w]; }
                a.deg[row] = ssum;
            }
            __syncthreads();
            int base = wbase[wid] + inc - cnt;
            unsigned short* dst = a.nbrs + (size_t)row * 512 + base;
            int col0 = t * 8, k = 0;
            while (m8) {
                int b = __ffs(m8) - 1;
                m8 &= m8 - 1;
                dst[k++] = (unsigned short)(col0 + b);
            }
        }
        // weight packs (blocks 0..127), LDS-transposed
        if (blk < 128) {
            float (*T)[65] = (float(*)[65])(LDSU + 1024);
            __syncthreads();
            if (blk < 64) {
                const int h = blk >> 3, f0 = (blk & 7) * 64;
                #pragma unroll
                for (int i = 0; i < 8; ++i) {
                    int idx = i * 512 + t;
                    int fr = idx >> 6, k = idx & 63;
                    T[fr][k] = a.Ws[h * 32768 + (f0 + fr) * 64 + k];
                }
                __syncthreads();
                #pragma unroll
                for (int i = 0; i < 8; ++i) {
                    int idx = i * 512 + t;
                    int k = idx >> 6, fr = idx & 63;
                    unsigned short hh, ll;
                    split2(T[fr][k], hh, ll);
                    size_t dsti = (size_t)(h * 64 + k) * 512 + f0 + fr;
                    a.wshi[dsti] = hh; a.wslo[dsti] = ll;
                }
            } else {
                const int b2 = blk - 64;
                const int c0 = (b2 >> 3) * 64, f0 = (b2 & 7) * 64;
                #pragma unroll
                for (int i = 0; i < 8; ++i) {
                    int idx = i * 512 + t;
                    int fr = idx >> 6, k = idx & 63;
                    T[fr][k] = a.Wo[(size_t)(f0 + fr) * 512 + c0 + k];
                }
                __syncthreads();
                #pragma unroll
                for (int i = 0; i < 8; ++i) {
                    int idx = i * 512 + t;
                    int k = idx >> 6, fr = idx & 63;
                    unsigned short hh, ll;
                    split2(T[fr][k], hh, ll);
                    size_t dsti = (size_t)(c0 + k) * 512 + f0 + fr;
                    a.wohi[dsti] = hh; a.wolo[dsti] = ll;
                }
            }
        }
        // x split: 1024 float4 per block
        {
            #pragma unroll
            for (int q = 0; q < 2; ++q) {
                int i = blk * 1024 + q * 512 + t;
                float4 v = ((const float4*)a.x)[i];
                ushort4 h, l;
                split2(v.x, h.x, l.x); split2(v.y, h.y, l.y);
                split2(v.z, h.z, l.z); split2(v.w, h.w, l.w);
                ((ushort4*)a.xhi)[i] = h;
                ((ushort4*)a.xlo)[i] = l;
            }
        }
    }
    __threadfence();
    grid.sync();

    // ---- P1: gemm1 (+ s1/d1 epilogue) ----
    gemm_phase<false>(a.xhi, a.xlo, a.wshi, a.wslo, a.a1, a.a2,
                      a.Wh, a.sbuf, a.dbuf, LDSU, blk, t);
    __threadfence();
    grid.sync();

    // ---- P2: attn layer 1 (H=8), 2 rows/block x 4 iters ----
    for (int it = 0; it < 4; ++it) {
        const int row = it * 1024 + blk * 2 + (t >> 8);
        attn_one<8, true, false>(LDSU, t, row, a.Wh, a.sbuf, a.dbuf,
                                 a.nbrs, a.deg, nullptr, a.hch, a.hcl);
    }
    __threadfence();
    grid.sync();

    // ---- P3: gemm2 (+ spart/dpart epilogue) ----
    gemm_phase<true>(a.hch, a.hcl, a.wohi, a.wolo, a.ao1, a.ao2,
                     a.Who, a.spart, a.dpart, LDSU, blk, t);
    __threadfence();
    grid.sync();

    // ---- P4: attn layer 2 (H=1) ----
    for (int it = 0; it < 4; ++it) {
        const int row = it * 1024 + blk * 2 + (t >> 8);
        attn_one<1, false, true>(LDSU, t, row, a.Who, a.spart, a.dpart,
                                 a.nbrs, a.deg, a.out, nullptr, nullptr);
    }
}

// ================= fallback: round-6 five-kernel path =================

__global__ __launch_bounds__(256) void prep_fb(
        const float* __restrict__ adj, const float* __restrict__ Ws,
        const float* __restrict__ Wo, const float* __restrict__ x,
        unsigned short* __restrict__ nbr, int* __restrict__ deg,
        unsigned short* __restrict__ wshi, unsigned short* __restrict__ wslo,
        unsigned short* __restrict__ wohi, unsigned short* __restrict__ wolo,
        unsigned short* __restrict__ xhi, unsigned short* __restrict__ xlo, int N) {
    __shared__ int wtot[4];
    __shared__ int wbase[4];
    __shared__ float T[64][65];
    int b = blockIdx.x;
    const int t = threadIdx.x;
    if (b < 4096) {
        const int lane = t & 63, wid = t >> 6, row = b;
        const float4* arow = (const float4*)(adj + (size_t)row * N);
        unsigned mask16 = 0;
        #pragma unroll
        for (int q = 0; q < 4; ++q) {
            float4 v = arow[t * 4 + q];
            if (v.x > 0.f) mask16 |= 1u << (q * 4 + 0);
            if (v.y > 0.f) mask16 |= 1u << (q * 4 + 1);
            if (v.z > 0.f) mask16 |= 1u << (q * 4 + 2);
            if (v.w > 0.f) mask16 |= 1u << (q * 4 + 3);
        }
        int cnt = __popc(mask16);
        int inc = cnt;
        #pragma unroll
        for (int off = 1; off < 64; off <<= 1) {
            int nv = __shfl_up(inc, off);
            if (lane >= off) inc += nv;
        }
        if (lane == 63) wtot[wid] = inc;
        __syncthreads();
        if (t == 0) {
            int s = 0;
            #pragma unroll
            for (int w = 0; w < 4; ++w) { wbase[w] = s; s += wtot[w]; }
            deg[row] = s;
        }
        __syncthreads();
        int base = wbase[wid] + inc - cnt;
        unsigned short* dst = nbr + (size_t)row * 512 + base;
        int col0 = t * 16, k = 0;
        while (mask16) {
            int bi = __ffs(mask16) - 1;
            mask16 &= mask16 - 1;
            dst[k++] = (unsigned short)(col0 + bi);
        }
        return;
    }
    b -= 4096;
    if (b < 64) {
        const int h = b >> 3, f0 = (b & 7) * 64;
        #pragma unroll
        for (int i = 0; i < 16; ++i) {
            int idx = i * 256 + t;
            int fr = idx >> 6, k = idx & 63;
            T[fr][k] = Ws[h * 32768 + (f0 + fr) * 64 + k];
        }
        __syncthreads();
        #pragma unroll
        for (int i = 0; i < 16; ++i) {
            int idx = i * 256 + t;
            int k = idx >> 6, fr = idx & 63;
            unsigned short hh, ll;
            split2(T[fr][k], hh, ll);
            size_t dst = (size_t)(h * 64 + k) * 512 + f0 + fr;
            wshi[dst] = hh; wslo[dst] = ll;
        }
        return;
    }
    b -= 64;
    if (b < 64) {
        const int c0 = (b >> 3) * 64, f0 = (b & 7) * 64;
        #pragma unroll
        for (int i = 0; i < 16; ++i) {
            int idx = i * 256 + t;
            int fr = idx >> 6, k = idx & 63;
            T[fr][k] = Wo[(size_t)(f0 + fr) * 512 + c0 + k];
        }
        __syncthreads();
        #pragma unroll
        for (int i = 0; i < 16; ++i) {
            int idx = i * 256 + t;
            int k = idx >> 6, fr = idx & 63;
            unsigned short hh, ll;
            split2(T[fr][k], hh, ll);
            size_t dst = (size_t)(c0 + k) * 512 + f0 + fr;
            wohi[dst] = hh; wolo[dst] = ll;
        }
        return;
    }
    b -= 64;
    {
        int i = b * 256 + t;
        float4 v = ((const float4*)x)[i];
        ushort4 h, l;
        split2(v.x, h.x, l.x); split2(v.y, h.y, l.y);
        split2(v.z, h.z, l.z); split2(v.w, h.w, l.w);
        ((ushort4*)xhi)[i] = h;
        ((ushort4*)xlo)[i] = l;
    }
}

template<bool PART>
__global__ __launch_bounds__(256) void gemm_fb(
        const unsigned short* __restrict__ Ahi, const unsigned short* __restrict__ Alo,
        const unsigned short* __restrict__ Bhi, const unsigned short* __restrict__ Blo,
        const float* __restrict__ a1v, const float* __restrict__ a2v,
        float* __restrict__ C, float* __restrict__ sdst, float* __restrict__ ddst,
        int M, int K, int Nc) {
    __shared__ char lds[65536];
    const int t = threadIdx.x, lane = t & 63, wid = t >> 6;
    const int bm0 = blockIdx.y * 64, bn0 = blockIdx.x * 64;
    const int r0 = t >> 3;
    const int sc8 = (((t & 7) ^ ((t >> 3) & 7)) << 3);
    const size_t aoff = (size_t)(bm0 + r0) * K + sc8;
    const size_t boff = (size_t)(bn0 + r0) * K + sc8;
    const size_t half = (size_t)32 * K;
    auto stage = [&](char* dst, int k0) {
        gl16(Ahi + aoff + k0,        dst + 0 * 4096 + t * 16);
        gl16(Ahi + aoff + half + k0, dst + 1 * 4096 + t * 16);
        gl16(Alo + aoff + k0,        dst + 2 * 4096 + t * 16);
        gl16(Alo + aoff + half + k0, dst + 3 * 4096 + t * 16);
        gl16(Bhi + boff + k0,        dst + 4 * 4096 + t * 16);
        gl16(Bhi + boff + half + k0, dst + 5 * 4096 + t * 16);
        gl16(Blo + boff + k0,        dst + 6 * 4096 + t * 16);
        gl16(Blo + boff + half + k0, dst + 7 * 4096 + t * 16);
    };
    f32x4 acc00 = {0,0,0,0}, acc01 = {0,0,0,0}, acc10 = {0,0,0,0}, acc11 = {0,0,0,0};
    const int mq = (wid >> 1) * 32, nq = (wid & 1) * 32;
    const int rl = lane & 15, hl = lane >> 4;
    const int swz = rl & 7;
    auto compute = [&](const char* Lb) {
        const char* Ah_ = Lb;
        const char* Al_ = Lb + 8192;
        const char* Bh_ = Lb + 16384;
        const char* Bl_ = Lb + 24576;
        #pragma unroll
        for (int s = 0; s < 2; ++s) {
            const int ch = ((s * 4 + hl) ^ swz) * 16;
            const int ra0 = (mq + rl) * 128, ra1 = ra0 + 16 * 128;
            const int rb0 = (nq + rl) * 128, rb1 = rb0 + 16 * 128;
            bf16x8 A0h = *(const bf16x8*)(Ah_ + ra0 + ch);
            bf16x8 A1h = *(const bf16x8*)(Ah_ + ra1 + ch);
            bf16x8 A0l = *(const bf16x8*)(Al_ + ra0 + ch);
            bf16x8 A1l = *(const bf16x8*)(Al_ + ra1 + ch);
            bf16x8 B0h = *(const bf16x8*)(Bh_ + rb0 + ch);
            bf16x8 B1h = *(const bf16x8*)(Bh_ + rb1 + ch);
            bf16x8 B0l = *(const bf16x8*)(Bl_ + rb0 + ch);
            bf16x8 B1l = *(const bf16x8*)(Bl_ + rb1 + ch);
            acc00 = __builtin_amdgcn_mfma_f32_16x16x32_bf16(A0h, B0h, acc00, 0, 0, 0);
            acc01 = __builtin_amdgcn_mfma_f32_16x16x32_bf16(A0h, B1h, acc01, 0, 0, 0);
            acc10 = __builtin_amdgcn_mfma_f32_16x16x32_bf16(A1h, B0h, acc10, 0, 0, 0);
            acc11 = __builtin_amdgcn_mfma_f32_16x16x32_bf16(A1h, B1h, acc11, 0, 0, 0);
            acc00 = __builtin_amdgcn_mfma_f32_16x16x32_bf16(A0h, B0l, acc00, 0, 0, 0);
            acc01 = __builtin_amdgcn_mfma_f32_16x16x32_bf16(A0h, B1l, acc01, 0, 0, 0);
            acc10 = __builtin_amdgcn_mfma_f32_16x16x32_bf16(A1h, B0l, acc10, 0, 0, 0);
            acc11 = __builtin_amdgcn_mfma_f32_16x16x32_bf16(A1h, B1l, acc11, 0, 0, 0);
            acc00 = __builtin_amdgcn_mfma_f32_16x16x32_bf16(A0l, B0h, acc00, 0, 0, 0);
            acc01 = __builtin_amdgcn_mfma_f32_16x16x32_bf16(A0l, B1h, acc01, 0, 0, 0);
            acc10 = __builtin_amdgcn_mfma_f32_16x16x32_bf16(A1l, B0h, acc10, 0, 0, 0);
            acc11 = __builtin_amdgcn_mfma_f32_16x16x32_bf16(A1l, B1h, acc11, 0, 0, 0);
        }
    };
    stage(lds, 0);
    __syncthreads();
    for (int st = 0; st < 8; ++st) {
        char* cur = lds + (st & 1) * 32768;
        if (st + 1 < 8) stage(lds + ((st + 1) & 1) * 32768, (st + 1) * 64);
        compute(cur);
        __syncthreads();
    }
    const int orow = hl * 4;
    #pragma unroll
    for (int j = 0; j < 4; ++j) {
        C[(size_t)(bm0 + mq + orow + j) * Nc + bn0 + nq + rl]           = acc00[j];
        C[(size_t)(bm0 + mq + orow + j) * Nc + bn0 + nq + 16 + rl]      = acc01[j];
        C[(size_t)(bm0 + mq + 16 + orow + j) * Nc + bn0 + nq + rl]      = acc10[j];
        C[(size_t)(bm0 + mq + 16 + orow + j) * Nc + bn0 + nq + 16 + rl] = acc11[j];
    }
    const int C0 = bn0 + nq + rl, C1 = C0 + 16;
    const float a1c0 = a1v[C0], a1c1 = a1v[C1];
    const float a2c0 = a2v[C0], a2c1 = a2v[C1];
    float ps0[4], ps1[4], pd0[4], pd1[4];
    #pragma unroll
    for (int j = 0; j < 4; ++j) {
        ps0[j] = acc00[j] * a1c0 + acc01[j] * a1c1;
        ps1[j] = acc10[j] * a1c0 + acc11[j] * a1c1;
        pd0[j] = acc00[j] * a2c0 + acc01[j] * a2c1;
        pd1[j] = acc10[j] * a2c0 + acc11[j] * a2c1;
    }
    #pragma unroll
    for (int off = 1; off < 16; off <<= 1) {
        #pragma unroll
        for (int j = 0; j < 4; ++j) {
            ps0[j] += __shfl_xor(ps0[j], off);
            ps1[j] += __shfl_xor(ps1[j], off);
            pd0[j] += __shfl_xor(pd0[j], off);
            pd1[j] += __shfl_xor(pd1[j], off);
        }
    }
    float* eps = (float*)lds;
    if ((wid & 1) == 0 && rl == 0) {
        #pragma unroll
        for (int j = 0; j < 4; ++j) {
            eps[mq + orow + j]           = ps0[j];
            eps[mq + 16 + orow + j]      = ps1[j];
            eps[64 + mq + orow + j]      = pd0[j];
            eps[64 + mq + 16 + orow + j] = pd1[j];
        }
    }
    __syncthreads();
    if ((wid & 1) == 1 && rl == 0) {
        #pragma unroll
        for (int j = 0; j < 4; ++j) {
            const int t0 = mq + orow + j, t1 = t0 + 16;
            if constexpr (PART) {
                sdst[(size_t)(bm0 + t0) * 8 + blockIdx.x] = ps0[j] + eps[t0];
                sdst[(size_t)(bm0 + t1) * 8 + blockIdx.x] = ps1[j] + eps[t1];
                ddst[(size_t)(bm0 + t0) * 8 + blockIdx.x] = pd0[j] + eps[64 + t0];
                ddst[(size_t)(bm0 + t1) * 8 + blockIdx.x] = pd1[j] + eps[64 + t1];
            } else {
                float* sh_ = sdst + (size_t)blockIdx.x * M;
                float* dh_ = ddst + (size_t)blockIdx.x * M;
                sh_[bm0 + t0] = ps0[j] + eps[t0];
                sh_[bm0 + t1] = ps1[j] + eps[t1];
                dh_[bm0 + t0] = pd0[j] + eps[64 + t0];
                dh_[bm0 + t1] = pd1[j] + eps[64 + t1];
            }
        }
    }
}

template<int H, bool SPLIT, bool PART8>
__global__ __launch_bounds__(256) void attn_fb(
        const float* __restrict__ Wh, const float* __restrict__ s,
        const float* __restrict__ d, const unsigned short* __restrict__ nbr,
        const int* __restrict__ deg, float* __restrict__ out,
        unsigned short* __restrict__ ohi, unsigned short* __restrict__ olo, int N) {
    constexpr int F = 512, NH = F / H, CAP = 512, GS = 256 / H;
    __shared__ int nb[CAP];
    __shared__ float p[H][CAP];
    __shared__ float lred[H];
    __shared__ float red[4];
    const int t = threadIdx.x, lane = t & 63, row = blockIdx.x;
    const int M = deg[row];
    for (int j = t; j < M; j += 256) nb[j] = nbr[(size_t)row * 512 + j];
    __syncthreads();
    const int h = t / GS, sub = t % GS;
    float sh;
    if constexpr (PART8) {
        const float4* sp = (const float4*)(s + (size_t)row * 8);
        float4 s0 = sp[0], s1 = sp[1];
        sh = ((s0.x + s0.y) + (s0.z + s0.w)) + ((s1.x + s1.y) + (s1.z + s1.w));
    } else {
        sh = s[h * N + row];
    }
    float lm = -INFINITY;
    for (int j = sub; j < M; j += GS) {
        float dv;
        if constexpr (PART8) {
            const float4* dp = (const float4*)(d + (size_t)nb[j] * 8);
            float4 d0 = dp[0], d1 = dp[1];
            dv = ((d0.x + d0.y) + (d0.z + d0.w)) + ((d1.x + d1.y) + (d1.z + d1.w));
        } else {
            dv = d[h * N + nb[j]];
        }
        float e = sh + dv;
        e = e > 0.f ? e : 0.2f * e;
        p[h][j] = e;
        lm = fmaxf(lm, e);
    }
    if constexpr (GS <= 64) {
        #pragma unroll
        for (int off = GS / 2; off; off >>= 1) lm = fmaxf(lm, __shfl_xor(lm, off));
    } else {
        #pragma unroll
        for (int off = 32; off; off >>= 1) lm = fmaxf(lm, __shfl_xor(lm, off));
        if (lane == 0) red[t >> 6] = lm;
        __syncthreads();
        lm = fmaxf(fmaxf(red[0], red[1]), fmaxf(red[2], red[3]));
    }
    float ls = 0.f;
    for (int j = sub; j < M; j += GS) {
        float pe = expf(p[h][j] - lm);
        p[h][j] = pe;
        ls += pe;
    }
    if constexpr (GS <= 64) {
        #pragma unroll
        for (int off = GS / 2; off; off >>= 1) ls += __shfl_xor(ls, off);
    } else {
        #pragma unroll
        for (int off = 32; off; off >>= 1) ls += __shfl_xor(ls, off);
        __syncthreads();
        if (lane == 0) red[t >> 6] = ls;
        __syncthreads();
        ls = red[0] + red[1] + red[2] + red[3];
    }
    if (sub == 0) lred[h] = ls;
    __syncthreads();
    const int c = 2 * t;
    const int hc = c / NH;
    const float inv = 1.f / lred[hc];
    const float* base = Wh + c;
    float ax = 0.f, ay = 0.f;
    #pragma unroll 4
    for (int j = 0; j < M; ++j) {
        float pw = p[hc][j];
        const float2 w = *(const float2*)(base + (size_t)nb[j] * F);
        ax += pw * w.x; ay += pw * w.y;
    }
    ax *= inv; ay *= inv;
    ax = ax > 0.f ? ax : expm1f(ax);
    ay = ay > 0.f ? ay : expm1f(ay);
    if constexpr (SPLIT) {
        unsigned short hx, lx, hy, ly;
        split2(ax, hx, lx); split2(ay, hy, ly);
        ushort2 hv, lv;
        hv.x = hx; hv.y = hy; lv.x = lx; lv.y = ly;
        *(ushort2*)(ohi + (size_t)row * F + c) = hv;
        *(ushort2*)(olo + (size_t)row * F + c) = lv;
    } else {
        float2 o; o.x = ax; o.y = ay;
        *(float2*)(out + (size_t)row * F + c) = o;
    }
}

extern "C" void kernel_launch(void* const* d_in, const int* in_sizes, int n_in,
                              void* d_out, int out_size, void* d_ws, size_t ws_size,
                              hipStream_t stream) {
    const float* x   = (const float*)d_in[0];
    const float* adj = (const float*)d_in[2];
    const float* Ws  = (const float*)d_in[3];
    const float* a1  = (const float*)d_in[4];
    const float* a2  = (const float*)d_in[5];
    const float* Wo  = (const float*)d_in[6];
    const float* ao1 = (const float*)d_in[7];
    const float* ao2 = (const float*)d_in[8];
    float* out = (float*)d_out;
    const int N = GN;

    float* ws    = (float*)d_ws;
    float* Wh    = ws;                    // 4096*512 f32
    float* Who   = Wh + 2097152;          // 4096*512 f32
    float* sbuf  = Who + 2097152;         // 8*4096
    float* dbuf  = sbuf + 32768;          // 8*4096
    float* spart = dbuf + 32768;          // 4096*8
    float* dpart = spart + 32768;         // 4096*8
    unsigned short* nbrs = (unsigned short*)(dpart + 32768); // 4096*512 u16
    int*            deg  = (int*)(nbrs + 2097152);           // 4096 i32
    unsigned short* xhi  = (unsigned short*)(deg + 4096);    // 4096*512 u16
    unsigned short* xlo  = xhi + 2097152;
    unsigned short* hch  = xlo + 2097152;
    unsigned short* hcl  = hch + 2097152;
    unsigned short* wshi = hcl + 2097152;
    unsigned short* wslo = wshi + 262144;
    unsigned short* wohi = wslo + 262144;
    unsigned short* wolo = wohi + 262144;

    GArgs ga;
    ga.adj = adj; ga.Ws = Ws; ga.Wo = Wo; ga.x = x;
    ga.a1 = a1; ga.a2 = a2; ga.ao1 = ao1; ga.ao2 = ao2;
    ga.out = out; ga.Wh = Wh; ga.Who = Who;
    ga.sbuf = sbuf; ga.dbuf = dbuf; ga.spart = spart; ga.dpart = dpart;
    ga.nbrs = nbrs; ga.deg = deg;
    ga.xhi = xhi; ga.xlo = xlo; ga.hch = hch; ga.hcl = hcl;
    ga.wshi = wshi; ga.wslo = wslo; ga.wohi = wohi; ga.wolo = wolo;
    void* kargs[] = { (void*)&ga };

    hipError_t err = hipLaunchCooperativeKernel((const void*)gat_mega,
                                                dim3(512), dim3(512), kargs, 0, stream);
    if (err != hipSuccess) {
        // fallback: round-6 five-kernel path
        hipLaunchKernelGGL(prep_fb, dim3(6272), dim3(256), 0, stream,
                           adj, Ws, Wo, x, nbrs, deg, wshi, wslo, wohi, wolo, xhi, xlo, N);
        hipLaunchKernelGGL((gemm_fb<false>), dim3(8, 64), dim3(256), 0, stream,
                           xhi, xlo, wshi, wslo, a1, a2, Wh, sbuf, dbuf, 4096, 512, 512);
        hipLaunchKernelGGL((attn_fb<8, true, false>), dim3(4096), dim3(256), 0, stream,
                           Wh, sbuf, dbuf, nbrs, deg, (float*)nullptr, hch, hcl, N);
        hipLaunchKernelGGL((gemm_fb<true>), dim3(8, 64), dim3(256), 0, stream,
                           hch, hcl, wohi, wolo, ao1, ao2, Who, spart, dpart, 4096, 512, 512);
        hipLaunchKernelGGL((attn_fb<1, false, true>), dim3(4096), dim3(256), 0, stream,
                           Who, spart, dpart, nbrs, deg, out, (unsigned short*)nullptr,
                           (unsigned short*)nullptr, N);
    }
}

// Round 10
// 103.052 us; speedup vs baseline: 6.4263x; 6.4263x over previous
//
#include <hip/hip_runtime.h>
#include <hip/hip_bf16.h>
#include <math.h>

// GAT forward, N=4096, F=512, H=8, NH=64.
// Round 10: revert to r6 5-kernel structure. Adds (1) XCD-aware block swizzle
// in gemm (same-bm blocks pinned to one XCD -> A-panel L2 reuse), (2) s/d in
// [node][8] layout + vectorized attn8 logit gathers (8x fewer transactions).

#define GN 4096
#define GF 512

typedef __attribute__((ext_vector_type(8))) short bf16x8;
typedef __attribute__((ext_vector_type(4))) float f32x4;

__device__ inline unsigned short f2bf(float f) {
    unsigned u = __float_as_uint(f);
    return (unsigned short)((u + 0x7fffu + ((u >> 16) & 1u)) >> 16);
}
__device__ inline float bf2f(unsigned short h) {
    return __uint_as_float((unsigned)h << 16);
}
__device__ inline void split2(float v, unsigned short& h, unsigned short& l) {
    h = f2bf(v);
    l = f2bf(v - bf2f(h));
}
__device__ inline void gl16(const void* g, void* l) {
    __builtin_amdgcn_global_load_lds((const __attribute__((address_space(1))) unsigned int*)g,
                                     (__attribute__((address_space(3))) unsigned int*)l, 16, 0, 0);
}

// ---- fused prep: extract_nbrs + LDS-transposed packs of Ws/Wo + split x ----
// grid = 4096 (extract) + 64 (Ws) + 64 (Wo) + 2048 (x split) = 6272
__global__ __launch_bounds__(256) void prep(
        const float* __restrict__ adj, const float* __restrict__ Ws,
        const float* __restrict__ Wo, const float* __restrict__ x,
        unsigned short* __restrict__ nbr, int* __restrict__ deg,
        unsigned short* __restrict__ wshi, unsigned short* __restrict__ wslo,
        unsigned short* __restrict__ wohi, unsigned short* __restrict__ wolo,
        unsigned short* __restrict__ xhi, unsigned short* __restrict__ xlo, int N) {
    __shared__ int wtot[4];
    __shared__ int wbase[4];
    __shared__ float T[64][65];
    int b = blockIdx.x;
    const int t = threadIdx.x;
    if (b < 4096) {                       // neighbor extraction, row = b
        const int lane = t & 63, wid = t >> 6, row = b;
        const float4* arow = (const float4*)(adj + (size_t)row * N);
        unsigned mask16 = 0;
        #pragma unroll
        for (int q = 0; q < 4; ++q) {
            float4 v = arow[t * 4 + q];
            if (v.x > 0.f) mask16 |= 1u << (q * 4 + 0);
            if (v.y > 0.f) mask16 |= 1u << (q * 4 + 1);
            if (v.z > 0.f) mask16 |= 1u << (q * 4 + 2);
            if (v.w > 0.f) mask16 |= 1u << (q * 4 + 3);
        }
        int cnt = __popc(mask16);
        int inc = cnt;
        #pragma unroll
        for (int off = 1; off < 64; off <<= 1) {
            int nv = __shfl_up(inc, off);
            if (lane >= off) inc += nv;
        }
        if (lane == 63) wtot[wid] = inc;
        __syncthreads();
        if (t == 0) {
            int s = 0;
            #pragma unroll
            for (int w = 0; w < 4; ++w) { wbase[w] = s; s += wtot[w]; }
            deg[row] = s;
        }
        __syncthreads();
        int base = wbase[wid] + inc - cnt;
        unsigned short* dst = nbr + (size_t)row * 512 + base;
        int col0 = t * 16;
        int k = 0;
        while (mask16) {
            int bi = __ffs(mask16) - 1;
            mask16 &= mask16 - 1;
            dst[k++] = (unsigned short)(col0 + bi);
        }
        return;
    }
    b -= 4096;
    if (b < 64) {                         // Ws[h][f][k] -> Bt[h*64+k][f], tiled
        const int h = b >> 3, f0 = (b & 7) * 64;
        #pragma unroll
        for (int i = 0; i < 16; ++i) {
            int idx = i * 256 + t;
            int fr = idx >> 6, k = idx & 63;
            T[fr][k] = Ws[h * 32768 + (f0 + fr) * 64 + k];
        }
        __syncthreads();
        #pragma unroll
        for (int i = 0; i < 16; ++i) {
            int idx = i * 256 + t;
            int k = idx >> 6, fr = idx & 63;
            unsigned short hh, ll;
            split2(T[fr][k], hh, ll);
            size_t dst = (size_t)(h * 64 + k) * 512 + f0 + fr;
            wshi[dst] = hh; wslo[dst] = ll;
        }
        return;
    }
    b -= 64;
    if (b < 64) {                         // Wo[f][c] -> Bt[c][f], tiled
        const int c0 = (b >> 3) * 64, f0 = (b & 7) * 64;
        #pragma unroll
        for (int i = 0; i < 16; ++i) {
            int idx = i * 256 + t;
            int fr = idx >> 6, k = idx & 63;
            T[fr][k] = Wo[(size_t)(f0 + fr) * 512 + c0 + k];
        }
        __syncthreads();
        #pragma unroll
        for (int i = 0; i < 16; ++i) {
            int idx = i * 256 + t;
            int k = idx >> 6, fr = idx & 63;
            unsigned short hh, ll;
            split2(T[fr][k], hh, ll);
            size_t dst = (size_t)(c0 + k) * 512 + f0 + fr;
            wohi[dst] = hh; wolo[dst] = ll;
        }
        return;
    }
    b -= 64;
    {                                     // split x -> hi/lo, 2048 blocks
        int i = b * 256 + t;              // [0, 524288)
        float4 v = ((const float4*)x)[i];
        ushort4 h, l;
        split2(v.x, h.x, l.x); split2(v.y, h.y, l.y);
        split2(v.z, h.z, l.z); split2(v.w, h.w, l.w);
        ((ushort4*)xhi)[i] = h;
        ((ushort4*)xlo)[i] = l;
    }
}

// ---- MFMA GEMM: C = A@B; A hi/lo [M][K], B hi/lo [Nc][K]; 64x64 tile, BK=64,
// dbuf LDS, 3-term bf16 split, both-sides XOR swizzle.
// Grid: 512 blocks 1-D, XCD-aware swizzle: xcd = blk%8 -> same-bm groups on
// one XCD so the A panel is fetched into that XCD's L2 once, reused 8x.
// Epilogue: per-row dots over this block's 64 cols -> sdst/ddst[row*8 + bnI].
// (layer 1: bnI == head, full per-head value; layer 2: 64-col partial.)
__global__ __launch_bounds__(256) void gemm_3t(
        const unsigned short* __restrict__ Ahi, const unsigned short* __restrict__ Alo,
        const unsigned short* __restrict__ Bhi, const unsigned short* __restrict__ Blo,
        const float* __restrict__ a1v, const float* __restrict__ a2v,
        float* __restrict__ C, float* __restrict__ sdst, float* __restrict__ ddst,
        int M, int K, int Nc) {
    __shared__ char lds[65536];           // 2 buffers x 32KB (Ah|Al|Bh|Bl)
    const int t = threadIdx.x, lane = t & 63, wid = t >> 6;
    const int blk = blockIdx.x;
    const int bmI = (blk & 7) | ((blk >> 6) << 3);   // 0..63
    const int bnI = (blk >> 3) & 7;                  // 0..7
    const int bm0 = bmI * 64, bn0 = bnI * 64;
    const int r0 = t >> 3;
    const int sc8 = (((t & 7) ^ ((t >> 3) & 7)) << 3);   // swizzled chunk, elems
    const size_t aoff = (size_t)(bm0 + r0) * K + sc8;
    const size_t boff = (size_t)(bn0 + r0) * K + sc8;
    const size_t half = (size_t)32 * K;

    auto stage = [&](char* dst, int k0) {
        gl16(Ahi + aoff + k0,        dst + 0 * 4096 + t * 16);
        gl16(Ahi + aoff + half + k0, dst + 1 * 4096 + t * 16);
        gl16(Alo + aoff + k0,        dst + 2 * 4096 + t * 16);
        gl16(Alo + aoff + half + k0, dst + 3 * 4096 + t * 16);
        gl16(Bhi + boff + k0,        dst + 4 * 4096 + t * 16);
        gl16(Bhi + boff + half + k0, dst + 5 * 4096 + t * 16);
        gl16(Blo + boff + k0,        dst + 6 * 4096 + t * 16);
        gl16(Blo + boff + half + k0, dst + 7 * 4096 + t * 16);
    };

    f32x4 acc00 = {0,0,0,0}, acc01 = {0,0,0,0}, acc10 = {0,0,0,0}, acc11 = {0,0,0,0};
    const int mq = (wid >> 1) * 32, nq = (wid & 1) * 32;
    const int rl = lane & 15, hl = lane >> 4;
    const int swz = rl & 7;

    auto compute = [&](const char* Lb) {
        const char* Ah_ = Lb;
        const char* Al_ = Lb + 8192;
        const char* Bh_ = Lb + 16384;
        const char* Bl_ = Lb + 24576;
        #pragma unroll
        for (int s = 0; s < 2; ++s) {
            const int ch = ((s * 4 + hl) ^ swz) * 16;
            const int ra0 = (mq + rl) * 128, ra1 = ra0 + 16 * 128;
            const int rb0 = (nq + rl) * 128, rb1 = rb0 + 16 * 128;
            bf16x8 A0h = *(const bf16x8*)(Ah_ + ra0 + ch);
            bf16x8 A1h = *(const bf16x8*)(Ah_ + ra1 + ch);
            bf16x8 A0l = *(const bf16x8*)(Al_ + ra0 + ch);
            bf16x8 A1l = *(const bf16x8*)(Al_ + ra1 + ch);
            bf16x8 B0h = *(const bf16x8*)(Bh_ + rb0 + ch);
            bf16x8 B1h = *(const bf16x8*)(Bh_ + rb1 + ch);
            bf16x8 B0l = *(const bf16x8*)(Bl_ + rb0 + ch);
            bf16x8 B1l = *(const bf16x8*)(Bl_ + rb1 + ch);
            acc00 = __builtin_amdgcn_mfma_f32_16x16x32_bf16(A0h, B0h, acc00, 0, 0, 0);
            acc01 = __builtin_amdgcn_mfma_f32_16x16x32_bf16(A0h, B1h, acc01, 0, 0, 0);
            acc10 = __builtin_amdgcn_mfma_f32_16x16x32_bf16(A1h, B0h, acc10, 0, 0, 0);
            acc11 = __builtin_amdgcn_mfma_f32_16x16x32_bf16(A1h, B1h, acc11, 0, 0, 0);
            acc00 = __builtin_amdgcn_mfma_f32_16x16x32_bf16(A0h, B0l, acc00, 0, 0, 0);
            acc01 = __builtin_amdgcn_mfma_f32_16x16x32_bf16(A0h, B1l, acc01, 0, 0, 0);
            acc10 = __builtin_amdgcn_mfma_f32_16x16x32_bf16(A1h, B0l, acc10, 0, 0, 0);
            acc11 = __builtin_amdgcn_mfma_f32_16x16x32_bf16(A1h, B1l, acc11, 0, 0, 0);
            acc00 = __builtin_amdgcn_mfma_f32_16x16x32_bf16(A0l, B0h, acc00, 0, 0, 0);
            acc01 = __builtin_amdgcn_mfma_f32_16x16x32_bf16(A0l, B1h, acc01, 0, 0, 0);
            acc10 = __builtin_amdgcn_mfma_f32_16x16x32_bf16(A1l, B0h, acc10, 0, 0, 0);
            acc11 = __builtin_amdgcn_mfma_f32_16x16x32_bf16(A1l, B1h, acc11, 0, 0, 0);
        }
    };

    stage(lds, 0);
    __syncthreads();
    const int NT = K / 64;                // 8 steps
    for (int st = 0; st < NT; ++st) {
        char* cur = lds + (st & 1) * 32768;
        if (st + 1 < NT) stage(lds + ((st + 1) & 1) * 32768, (st + 1) * 64);
        compute(cur);
        __syncthreads();
    }

    const int orow = hl * 4;
    #pragma unroll
    for (int j = 0; j < 4; ++j) {
        C[(size_t)(bm0 + mq + orow + j) * Nc + bn0 + nq + rl]           = acc00[j];
        C[(size_t)(bm0 + mq + orow + j) * Nc + bn0 + nq + 16 + rl]      = acc01[j];
        C[(size_t)(bm0 + mq + 16 + orow + j) * Nc + bn0 + nq + rl]      = acc10[j];
        C[(size_t)(bm0 + mq + 16 + orow + j) * Nc + bn0 + nq + 16 + rl] = acc11[j];
    }

    // ---- fused s/d epilogue (exact fp32); writes [row][8] layout ----
    const int C0 = bn0 + nq + rl, C1 = C0 + 16;
    const float a1c0 = a1v[C0], a1c1 = a1v[C1];
    const float a2c0 = a2v[C0], a2c1 = a2v[C1];
    float ps0[4], ps1[4], pd0[4], pd1[4];
    #pragma unroll
    for (int j = 0; j < 4; ++j) {
        ps0[j] = acc00[j] * a1c0 + acc01[j] * a1c1;
        ps1[j] = acc10[j] * a1c0 + acc11[j] * a1c1;
        pd0[j] = acc00[j] * a2c0 + acc01[j] * a2c1;
        pd1[j] = acc10[j] * a2c0 + acc11[j] * a2c1;
    }
    #pragma unroll
    for (int off = 1; off < 16; off <<= 1) {
        #pragma unroll
        for (int j = 0; j < 4; ++j) {
            ps0[j] += __shfl_xor(ps0[j], off);
            ps1[j] += __shfl_xor(ps1[j], off);
            pd0[j] += __shfl_xor(pd0[j], off);
            pd1[j] += __shfl_xor(pd1[j], off);
        }
    }
    float* eps = (float*)lds;             // [0:64) s rows, [64:128) d rows
    if ((wid & 1) == 0 && rl == 0) {
        #pragma unroll
        for (int j = 0; j < 4; ++j) {
            eps[mq + orow + j]           = ps0[j];
            eps[mq + 16 + orow + j]      = ps1[j];
            eps[64 + mq + orow + j]      = pd0[j];
            eps[64 + mq + 16 + orow + j] = pd1[j];
        }
    }
    __syncthreads();
    if ((wid & 1) == 1 && rl == 0) {
        #pragma unroll
        for (int j = 0; j < 4; ++j) {
            const int t0 = mq + orow + j, t1 = t0 + 16;
            sdst[(size_t)(bm0 + t0) * 8 + bnI] = ps0[j] + eps[t0];
            sdst[(size_t)(bm0 + t1) * 8 + bnI] = ps1[j] + eps[t1];
            ddst[(size_t)(bm0 + t0) * 8 + bnI] = pd0[j] + eps[64 + t0];
            ddst[(size_t)(bm0 + t1) * 8 + bnI] = pd1[j] + eps[64 + t1];
        }
    }
}

// ---- attn layer 1 (H=8): vectorized logits from s/d [node][8]; writes hcat
// as hi/lo bf16. One block (256 thr) per row.
#define PS 516
__global__ __launch_bounds__(256) void attn8_kernel(
        const float* __restrict__ Wh, const float* __restrict__ s_t,
        const float* __restrict__ d_t, const unsigned short* __restrict__ nbr,
        const int* __restrict__ deg,
        unsigned short* __restrict__ ohi, unsigned short* __restrict__ olo, int N) {
    __shared__ int nb[512];
    __shared__ float p[8 * PS];
    __shared__ float lred[8];
    const int t = threadIdx.x, row = blockIdx.x;
    const int M = deg[row];
    for (int j = t; j < M; j += 256) nb[j] = nbr[(size_t)row * 512 + j];
    __syncthreads();
    // per-row s vector (same for all threads; L1 broadcast)
    const float4* sp = (const float4*)(s_t + (size_t)row * 8);
    const float4 sA = sp[0], sB = sp[1];
    const float shv[8] = {sA.x, sA.y, sA.z, sA.w, sB.x, sB.y, sB.z, sB.w};
    // j-parallel logits: one 32B gather per neighbor covers all 8 heads
    for (int j = t; j < M; j += 256) {
        const float4* dp = (const float4*)(d_t + (size_t)nb[j] * 8);
        const float4 dA = dp[0], dB = dp[1];
        const float dv[8] = {dA.x, dA.y, dA.z, dA.w, dB.x, dB.y, dB.z, dB.w};
        #pragma unroll
        for (int h = 0; h < 8; ++h) {
            float e = shv[h] + dv[h];
            e = e > 0.f ? e : 0.2f * e;   // leaky relu 0.2
            p[h * PS + j] = e;
        }
    }
    __syncthreads();
    // per-head softmax: 32-lane group per head (same reduction order as r6)
    const int h = t >> 5, sub = t & 31;
    float lm = -INFINITY;
    for (int j = sub; j < M; j += 32) lm = fmaxf(lm, p[h * PS + j]);
    #pragma unroll
    for (int off = 16; off; off >>= 1) lm = fmaxf(lm, __shfl_xor(lm, off));
    float ls = 0.f;
    for (int j = sub; j < M; j += 32) {
        float pe = expf(p[h * PS + j] - lm);
        p[h * PS + j] = pe;
        ls += pe;
    }
    #pragma unroll
    for (int off = 16; off; off >>= 1) ls += __shfl_xor(ls, off);
    if (sub == 0) lred[h] = ls;
    __syncthreads();
    // aggregate: thread owns cols 2t, 2t+1 (head hc == t>>5)
    const int c = 2 * t;
    const int hc = t >> 5;
    const float inv = 1.f / lred[hc];
    const float* base = Wh + c;
    float ax = 0.f, ay = 0.f;
    #pragma unroll 4
    for (int j = 0; j < M; ++j) {
        float pw = p[hc * PS + j];
        const float2 w = *(const float2*)(base + (size_t)nb[j] * 512);
        ax += pw * w.x; ay += pw * w.y;
    }
    ax *= inv; ay *= inv;
    ax = ax > 0.f ? ax : expm1f(ax);      // ELU (concat heads)
    ay = ay > 0.f ? ay : expm1f(ay);
    unsigned short hx, lx, hy, ly;
    split2(ax, hx, lx); split2(ay, hy, ly);
    ushort2 hv, lv;
    hv.x = hx; hv.y = hy; lv.x = lx; lv.y = ly;
    *(ushort2*)(ohi + (size_t)row * 512 + c) = hv;
    *(ushort2*)(olo + (size_t)row * 512 + c) = lv;
}

// ---- attn layer 2 (H=1): s/d are [row][8] partials; writes f32 out w/ ELU.
__global__ __launch_bounds__(256) void attn1_kernel(
        const float* __restrict__ Wh, const float* __restrict__ s,
        const float* __restrict__ d, const unsigned short* __restrict__ nbr,
        const int* __restrict__ deg, float* __restrict__ out, int N) {
    __shared__ int nb[512];
    __shared__ float p[512];
    __shared__ float lred[1];
    __shared__ float red[4];
    const int t = threadIdx.x, lane = t & 63, row = blockIdx.x;
    const int M = deg[row];
    for (int j = t; j < M; j += 256) nb[j] = nbr[(size_t)row * 512 + j];
    __syncthreads();
    const float4* sp = (const float4*)(s + (size_t)row * 8);
    float4 s0 = sp[0], s1 = sp[1];
    const float sh = ((s0.x + s0.y) + (s0.z + s0.w)) + ((s1.x + s1.y) + (s1.z + s1.w));
    float lm = -INFINITY;
    for (int j = t; j < M; j += 256) {
        const float4* dp = (const float4*)(d + (size_t)nb[j] * 8);
        float4 d0 = dp[0], d1 = dp[1];
        float dv = ((d0.x + d0.y) + (d0.z + d0.w)) + ((d1.x + d1.y) + (d1.z + d1.w));
        float e = sh + dv;
        e = e > 0.f ? e : 0.2f * e;
        p[j] = e;
        lm = fmaxf(lm, e);
    }
    #pragma unroll
    for (int off = 32; off; off >>= 1) lm = fmaxf(lm, __shfl_xor(lm, off));
    if (lane == 0) red[t >> 6] = lm;
    __syncthreads();
    lm = fmaxf(fmaxf(red[0], red[1]), fmaxf(red[2], red[3]));
    float ls = 0.f;
    for (int j = t; j < M; j += 256) {
        float pe = expf(p[j] - lm);
        p[j] = pe;
        ls += pe;
    }
    #pragma unroll
    for (int off = 32; off; off >>= 1) ls += __shfl_xor(ls, off);
    __syncthreads();
    if (lane == 0) red[t >> 6] = ls;
    __syncthreads();
    ls = red[0] + red[1] + red[2] + red[3];
    if (t == 0) lred[0] = ls;
    __syncthreads();
    const int c = 2 * t;
    const float inv = 1.f / lred[0];
    const float* base = Wh + c;
    float ax = 0.f, ay = 0.f;
    #pragma unroll 4
    for (int j = 0; j < M; ++j) {
        float pw = p[j];
        const float2 w = *(const float2*)(base + (size_t)nb[j] * 512);
        ax += pw * w.x; ay += pw * w.y;
    }
    ax *= inv; ay *= inv;
    ax = ax > 0.f ? ax : expm1f(ax);
    ay = ay > 0.f ? ay : expm1f(ay);
    float2 o; o.x = ax; o.y = ay;
    *(float2*)(out + (size_t)row * 512 + c) = o;
}

extern "C" void kernel_launch(void* const* d_in, const int* in_sizes, int n_in,
                              void* d_out, int out_size, void* d_ws, size_t ws_size,
                              hipStream_t stream) {
    const float* x   = (const float*)d_in[0];
    const float* adj = (const float*)d_in[2];
    const float* Ws  = (const float*)d_in[3];
    const float* a1  = (const float*)d_in[4];   // [H][64] flat, c = h*64+k
    const float* a2  = (const float*)d_in[5];
    const float* Wo  = (const float*)d_in[6];
    const float* ao1 = (const float*)d_in[7];   // [512]
    const float* ao2 = (const float*)d_in[8];
    float* out = (float*)d_out;
    const int N = GN;

    float* ws    = (float*)d_ws;
    float* Wh    = ws;                    // 4096*512 f32
    float* Who   = Wh + 2097152;          // 4096*512 f32
    float* s_t   = Who + 2097152;         // 4096*8
    float* d_t   = s_t + 32768;           // 4096*8
    float* spart = d_t + 32768;           // 4096*8
    float* dpart = spart + 32768;         // 4096*8
    unsigned short* nbrs = (unsigned short*)(dpart + 32768); // 4096*512 u16
    int*            deg  = (int*)(nbrs + 2097152);           // 4096 i32
    unsigned short* xhi  = (unsigned short*)(deg + 4096);    // 4096*512 u16
    unsigned short* xlo  = xhi + 2097152;
    unsigned short* hch  = xlo + 2097152;                    // hcat hi
    unsigned short* hcl  = hch + 2097152;                    // hcat lo
    unsigned short* wshi = hcl + 2097152;                    // 512*512
    unsigned short* wslo = wshi + 262144;
    unsigned short* wohi = wslo + 262144;
    unsigned short* wolo = wohi + 262144;

    hipLaunchKernelGGL(prep, dim3(6272), dim3(256), 0, stream,
                       adj, Ws, Wo, x, nbrs, deg, wshi, wslo, wohi, wolo, xhi, xlo, N);
    hipLaunchKernelGGL(gemm_3t, dim3(512), dim3(256), 0, stream,
                       xhi, xlo, wshi, wslo, a1, a2, Wh, s_t, d_t, 4096, 512, 512);
    hipLaunchKernelGGL(attn8_kernel, dim3(4096), dim3(256), 0, stream,
                       Wh, s_t, d_t, nbrs, deg, hch, hcl, N);
    hipLaunchKernelGGL(gemm_3t, dim3(512), dim3(256), 0, stream,
                       hch, hcl, wohi, wolo, ao1, ao2, Who, spart, dpart, 4096, 512, 512);
    hipLaunchKernelGGL(attn1_kernel, dim3(4096), dim3(256), 0, stream,
                       Who, spart, dpart, nbrs, deg, out, N);
}

// Round 11
// 78.220 us; speedup vs baseline: 8.4665x; 1.3175x over previous
//
#include <hip/hip_runtime.h>
#include <hip/hip_bf16.h>
#include <math.h>

// GAT forward, N=4096, F=512, H=8, NH=64.
// Round 11: aggregate operands (Wh, Who) stored fp16 -> gather traffic halves
// and 4MB working set fits per-XCD L2. Logits stay exact (s/d from f32 acc).
// Everything else = r10 (XCD swizzle, [node][8] s/d, vectorized logits).

#define GN 4096
#define GF 512

typedef __attribute__((ext_vector_type(8))) short bf16x8;
typedef __attribute__((ext_vector_type(4))) float f32x4;
typedef __attribute__((ext_vector_type(2))) _Float16 f16x2;

__device__ inline unsigned short f2bf(float f) {
    unsigned u = __float_as_uint(f);
    return (unsigned short)((u + 0x7fffu + ((u >> 16) & 1u)) >> 16);
}
__device__ inline float bf2f(unsigned short h) {
    return __uint_as_float((unsigned)h << 16);
}
__device__ inline void split2(float v, unsigned short& h, unsigned short& l) {
    h = f2bf(v);
    l = f2bf(v - bf2f(h));
}
__device__ inline void gl16(const void* g, void* l) {
    __builtin_amdgcn_global_load_lds((const __attribute__((address_space(1))) unsigned int*)g,
                                     (__attribute__((address_space(3))) unsigned int*)l, 16, 0, 0);
}

// ---- fused prep: extract_nbrs + LDS-transposed packs of Ws/Wo + split x ----
// grid = 4096 (extract) + 64 (Ws) + 64 (Wo) + 2048 (x split) = 6272
__global__ __launch_bounds__(256) void prep(
        const float* __restrict__ adj, const float* __restrict__ Ws,
        const float* __restrict__ Wo, const float* __restrict__ x,
        unsigned short* __restrict__ nbr, int* __restrict__ deg,
        unsigned short* __restrict__ wshi, unsigned short* __restrict__ wslo,
        unsigned short* __restrict__ wohi, unsigned short* __restrict__ wolo,
        unsigned short* __restrict__ xhi, unsigned short* __restrict__ xlo, int N) {
    __shared__ int wtot[4];
    __shared__ int wbase[4];
    __shared__ float T[64][65];
    int b = blockIdx.x;
    const int t = threadIdx.x;
    if (b < 4096) {                       // neighbor extraction, row = b
        const int lane = t & 63, wid = t >> 6, row = b;
        const float4* arow = (const float4*)(adj + (size_t)row * N);
        unsigned mask16 = 0;
        #pragma unroll
        for (int q = 0; q < 4; ++q) {
            float4 v = arow[t * 4 + q];
            if (v.x > 0.f) mask16 |= 1u << (q * 4 + 0);
            if (v.y > 0.f) mask16 |= 1u << (q * 4 + 1);
            if (v.z > 0.f) mask16 |= 1u << (q * 4 + 2);
            if (v.w > 0.f) mask16 |= 1u << (q * 4 + 3);
        }
        int cnt = __popc(mask16);
        int inc = cnt;
        #pragma unroll
        for (int off = 1; off < 64; off <<= 1) {
            int nv = __shfl_up(inc, off);
            if (lane >= off) inc += nv;
        }
        if (lane == 63) wtot[wid] = inc;
        __syncthreads();
        if (t == 0) {
            int s = 0;
            #pragma unroll
            for (int w = 0; w < 4; ++w) { wbase[w] = s; s += wtot[w]; }
            deg[row] = s;
        }
        __syncthreads();
        int base = wbase[wid] + inc - cnt;
        unsigned short* dst = nbr + (size_t)row * 512 + base;
        int col0 = t * 16;
        int k = 0;
        while (mask16) {
            int bi = __ffs(mask16) - 1;
            mask16 &= mask16 - 1;
            dst[k++] = (unsigned short)(col0 + bi);
        }
        return;
    }
    b -= 4096;
    if (b < 64) {                         // Ws[h][f][k] -> Bt[h*64+k][f], tiled
        const int h = b >> 3, f0 = (b & 7) * 64;
        #pragma unroll
        for (int i = 0; i < 16; ++i) {
            int idx = i * 256 + t;
            int fr = idx >> 6, k = idx & 63;
            T[fr][k] = Ws[h * 32768 + (f0 + fr) * 64 + k];
        }
        __syncthreads();
        #pragma unroll
        for (int i = 0; i < 16; ++i) {
            int idx = i * 256 + t;
            int k = idx >> 6, fr = idx & 63;
            unsigned short hh, ll;
            split2(T[fr][k], hh, ll);
            size_t dst = (size_t)(h * 64 + k) * 512 + f0 + fr;
            wshi[dst] = hh; wslo[dst] = ll;
        }
        return;
    }
    b -= 64;
    if (b < 64) {                         // Wo[f][c] -> Bt[c][f], tiled
        const int c0 = (b >> 3) * 64, f0 = (b & 7) * 64;
        #pragma unroll
        for (int i = 0; i < 16; ++i) {
            int idx = i * 256 + t;
            int fr = idx >> 6, k = idx & 63;
            T[fr][k] = Wo[(size_t)(f0 + fr) * 512 + c0 + k];
        }
        __syncthreads();
        #pragma unroll
        for (int i = 0; i < 16; ++i) {
            int idx = i * 256 + t;
            int k = idx >> 6, fr = idx & 63;
            unsigned short hh, ll;
            split2(T[fr][k], hh, ll);
            size_t dst = (size_t)(c0 + k) * 512 + f0 + fr;
            wohi[dst] = hh; wolo[dst] = ll;
        }
        return;
    }
    b -= 64;
    {                                     // split x -> hi/lo, 2048 blocks
        int i = b * 256 + t;              // [0, 524288)
        float4 v = ((const float4*)x)[i];
        ushort4 h, l;
        split2(v.x, h.x, l.x); split2(v.y, h.y, l.y);
        split2(v.z, h.z, l.z); split2(v.w, h.w, l.w);
        ((ushort4*)xhi)[i] = h;
        ((ushort4*)xlo)[i] = l;
    }
}

// ---- MFMA GEMM: C(fp16) = A@B; A hi/lo [M][K], B hi/lo [Nc][K]; 64x64 tile,
// BK=64, dbuf LDS, 3-term bf16 split, both-sides XOR swizzle, XCD swizzle.
// Epilogue: exact-f32 per-row dots over this block's 64 cols -> s/d[row*8+bnI].
__global__ __launch_bounds__(256) void gemm_3t(
        const unsigned short* __restrict__ Ahi, const unsigned short* __restrict__ Alo,
        const unsigned short* __restrict__ Bhi, const unsigned short* __restrict__ Blo,
        const float* __restrict__ a1v, const float* __restrict__ a2v,
        _Float16* __restrict__ C, float* __restrict__ sdst, float* __restrict__ ddst,
        int M, int K, int Nc) {
    __shared__ char lds[65536];           // 2 buffers x 32KB (Ah|Al|Bh|Bl)
    const int t = threadIdx.x, lane = t & 63, wid = t >> 6;
    const int blk = blockIdx.x;
    const int bmI = (blk & 7) | ((blk >> 6) << 3);   // 0..63
    const int bnI = (blk >> 3) & 7;                  // 0..7
    const int bm0 = bmI * 64, bn0 = bnI * 64;
    const int r0 = t >> 3;
    const int sc8 = (((t & 7) ^ ((t >> 3) & 7)) << 3);   // swizzled chunk, elems
    const size_t aoff = (size_t)(bm0 + r0) * K + sc8;
    const size_t boff = (size_t)(bn0 + r0) * K + sc8;
    const size_t half = (size_t)32 * K;

    auto stage = [&](char* dst, int k0) {
        gl16(Ahi + aoff + k0,        dst + 0 * 4096 + t * 16);
        gl16(Ahi + aoff + half + k0, dst + 1 * 4096 + t * 16);
        gl16(Alo + aoff + k0,        dst + 2 * 4096 + t * 16);
        gl16(Alo + aoff + half + k0, dst + 3 * 4096 + t * 16);
        gl16(Bhi + boff + k0,        dst + 4 * 4096 + t * 16);
        gl16(Bhi + boff + half + k0, dst + 5 * 4096 + t * 16);
        gl16(Blo + boff + k0,        dst + 6 * 4096 + t * 16);
        gl16(Blo + boff + half + k0, dst + 7 * 4096 + t * 16);
    };

    f32x4 acc00 = {0,0,0,0}, acc01 = {0,0,0,0}, acc10 = {0,0,0,0}, acc11 = {0,0,0,0};
    const int mq = (wid >> 1) * 32, nq = (wid & 1) * 32;
    const int rl = lane & 15, hl = lane >> 4;
    const int swz = rl & 7;

    auto compute = [&](const char* Lb) {
        const char* Ah_ = Lb;
        const char* Al_ = Lb + 8192;
        const char* Bh_ = Lb + 16384;
        const char* Bl_ = Lb + 24576;
        #pragma unroll
        for (int s = 0; s < 2; ++s) {
            const int ch = ((s * 4 + hl) ^ swz) * 16;
            const int ra0 = (mq + rl) * 128, ra1 = ra0 + 16 * 128;
            const int rb0 = (nq + rl) * 128, rb1 = rb0 + 16 * 128;
            bf16x8 A0h = *(const bf16x8*)(Ah_ + ra0 + ch);
            bf16x8 A1h = *(const bf16x8*)(Ah_ + ra1 + ch);
            bf16x8 A0l = *(const bf16x8*)(Al_ + ra0 + ch);
            bf16x8 A1l = *(const bf16x8*)(Al_ + ra1 + ch);
            bf16x8 B0h = *(const bf16x8*)(Bh_ + rb0 + ch);
            bf16x8 B1h = *(const bf16x8*)(Bh_ + rb1 + ch);
            bf16x8 B0l = *(const bf16x8*)(Bl_ + rb0 + ch);
            bf16x8 B1l = *(const bf16x8*)(Bl_ + rb1 + ch);
            acc00 = __builtin_amdgcn_mfma_f32_16x16x32_bf16(A0h, B0h, acc00, 0, 0, 0);
            acc01 = __builtin_amdgcn_mfma_f32_16x16x32_bf16(A0h, B1h, acc01, 0, 0, 0);
            acc10 = __builtin_amdgcn_mfma_f32_16x16x32_bf16(A1h, B0h, acc10, 0, 0, 0);
            acc11 = __builtin_amdgcn_mfma_f32_16x16x32_bf16(A1h, B1h, acc11, 0, 0, 0);
            acc00 = __builtin_amdgcn_mfma_f32_16x16x32_bf16(A0h, B0l, acc00, 0, 0, 0);
            acc01 = __builtin_amdgcn_mfma_f32_16x16x32_bf16(A0h, B1l, acc01, 0, 0, 0);
            acc10 = __builtin_amdgcn_mfma_f32_16x16x32_bf16(A1h, B0l, acc10, 0, 0, 0);
            acc11 = __builtin_amdgcn_mfma_f32_16x16x32_bf16(A1h, B1l, acc11, 0, 0, 0);
            acc00 = __builtin_amdgcn_mfma_f32_16x16x32_bf16(A0l, B0h, acc00, 0, 0, 0);
            acc01 = __builtin_amdgcn_mfma_f32_16x16x32_bf16(A0l, B1h, acc01, 0, 0, 0);
            acc10 = __builtin_amdgcn_mfma_f32_16x16x32_bf16(A1l, B0h, acc10, 0, 0, 0);
            acc11 = __builtin_amdgcn_mfma_f32_16x16x32_bf16(A1l, B1h, acc11, 0, 0, 0);
        }
    };

    stage(lds, 0);
    __syncthreads();
    const int NT = K / 64;                // 8 steps
    for (int st = 0; st < NT; ++st) {
        char* cur = lds + (st & 1) * 32768;
        if (st + 1 < NT) stage(lds + ((st + 1) & 1) * 32768, (st + 1) * 64);
        compute(cur);
        __syncthreads();
    }

    const int orow = hl * 4;
    #pragma unroll
    for (int j = 0; j < 4; ++j) {
        C[(size_t)(bm0 + mq + orow + j) * Nc + bn0 + nq + rl]           = (_Float16)acc00[j];
        C[(size_t)(bm0 + mq + orow + j) * Nc + bn0 + nq + 16 + rl]      = (_Float16)acc01[j];
        C[(size_t)(bm0 + mq + 16 + orow + j) * Nc + bn0 + nq + rl]      = (_Float16)acc10[j];
        C[(size_t)(bm0 + mq + 16 + orow + j) * Nc + bn0 + nq + 16 + rl] = (_Float16)acc11[j];
    }

    // ---- fused s/d epilogue (exact fp32 from acc registers); [row][8] ----
    const int C0 = bn0 + nq + rl, C1 = C0 + 16;
    const float a1c0 = a1v[C0], a1c1 = a1v[C1];
    const float a2c0 = a2v[C0], a2c1 = a2v[C1];
    float ps0[4], ps1[4], pd0[4], pd1[4];
    #pragma unroll
    for (int j = 0; j < 4; ++j) {
        ps0[j] = acc00[j] * a1c0 + acc01[j] * a1c1;
        ps1[j] = acc10[j] * a1c0 + acc11[j] * a1c1;
        pd0[j] = acc00[j] * a2c0 + acc01[j] * a2c1;
        pd1[j] = acc10[j] * a2c0 + acc11[j] * a2c1;
    }
    #pragma unroll
    for (int off = 1; off < 16; off <<= 1) {
        #pragma unroll
        for (int j = 0; j < 4; ++j) {
            ps0[j] += __shfl_xor(ps0[j], off);
            ps1[j] += __shfl_xor(ps1[j], off);
            pd0[j] += __shfl_xor(pd0[j], off);
            pd1[j] += __shfl_xor(pd1[j], off);
        }
    }
    float* eps = (float*)lds;             // [0:64) s rows, [64:128) d rows
    if ((wid & 1) == 0 && rl == 0) {
        #pragma unroll
        for (int j = 0; j < 4; ++j) {
            eps[mq + orow + j]           = ps0[j];
            eps[mq + 16 + orow + j]      = ps1[j];
            eps[64 + mq + orow + j]      = pd0[j];
            eps[64 + mq + 16 + orow + j] = pd1[j];
        }
    }
    __syncthreads();
    if ((wid & 1) == 1 && rl == 0) {
        #pragma unroll
        for (int j = 0; j < 4; ++j) {
            const int t0 = mq + orow + j, t1 = t0 + 16;
            sdst[(size_t)(bm0 + t0) * 8 + bnI] = ps0[j] + eps[t0];
            sdst[(size_t)(bm0 + t1) * 8 + bnI] = ps1[j] + eps[t1];
            ddst[(size_t)(bm0 + t0) * 8 + bnI] = pd0[j] + eps[64 + t0];
            ddst[(size_t)(bm0 + t1) * 8 + bnI] = pd1[j] + eps[64 + t1];
        }
    }
}

// ---- attn layer 1 (H=8): vectorized logits from s/d [node][8]; aggregate
// reads fp16 Wh; writes hcat hi/lo bf16. One block (256 thr) per row.
#define PS 516
__global__ __launch_bounds__(256) void attn8_kernel(
        const _Float16* __restrict__ Wh, const float* __restrict__ s_t,
        const float* __restrict__ d_t, const unsigned short* __restrict__ nbr,
        const int* __restrict__ deg,
        unsigned short* __restrict__ ohi, unsigned short* __restrict__ olo, int N) {
    __shared__ int nb[512];
    __shared__ float p[8 * PS];
    __shared__ float lred[8];
    const int t = threadIdx.x, row = blockIdx.x;
    const int M = deg[row];
    for (int j = t; j < M; j += 256) nb[j] = nbr[(size_t)row * 512 + j];
    __syncthreads();
    const float4* sp = (const float4*)(s_t + (size_t)row * 8);
    const float4 sA = sp[0], sB = sp[1];
    const float shv[8] = {sA.x, sA.y, sA.z, sA.w, sB.x, sB.y, sB.z, sB.w};
    for (int j = t; j < M; j += 256) {
        const float4* dp = (const float4*)(d_t + (size_t)nb[j] * 8);
        const float4 dA = dp[0], dB = dp[1];
        const float dv[8] = {dA.x, dA.y, dA.z, dA.w, dB.x, dB.y, dB.z, dB.w};
        #pragma unroll
        for (int h = 0; h < 8; ++h) {
            float e = shv[h] + dv[h];
            e = e > 0.f ? e : 0.2f * e;   // leaky relu 0.2
            p[h * PS + j] = e;
        }
    }
    __syncthreads();
    const int h = t >> 5, sub = t & 31;
    float lm = -INFINITY;
    for (int j = sub; j < M; j += 32) lm = fmaxf(lm, p[h * PS + j]);
    #pragma unroll
    for (int off = 16; off; off >>= 1) lm = fmaxf(lm, __shfl_xor(lm, off));
    float ls = 0.f;
    for (int j = sub; j < M; j += 32) {
        float pe = expf(p[h * PS + j] - lm);
        p[h * PS + j] = pe;
        ls += pe;
    }
    #pragma unroll
    for (int off = 16; off; off >>= 1) ls += __shfl_xor(ls, off);
    if (sub == 0) lred[h] = ls;
    __syncthreads();
    const int c = 2 * t;
    const int hc = t >> 5;
    const float inv = 1.f / lred[hc];
    const _Float16* base = Wh + c;
    float ax = 0.f, ay = 0.f;
    #pragma unroll 4
    for (int j = 0; j < M; ++j) {
        float pw = p[hc * PS + j];
        const f16x2 w = *(const f16x2*)(base + (size_t)nb[j] * 512);
        ax += pw * (float)w.x; ay += pw * (float)w.y;
    }
    ax *= inv; ay *= inv;
    ax = ax > 0.f ? ax : expm1f(ax);      // ELU (concat heads)
    ay = ay > 0.f ? ay : expm1f(ay);
    unsigned short hx, lx, hy, ly;
    split2(ax, hx, lx); split2(ay, hy, ly);
    ushort2 hv, lv;
    hv.x = hx; hv.y = hy; lv.x = lx; lv.y = ly;
    *(ushort2*)(ohi + (size_t)row * 512 + c) = hv;
    *(ushort2*)(olo + (size_t)row * 512 + c) = lv;
}

// ---- attn layer 2 (H=1): s/d [row][8] partials; aggregate reads fp16 Who;
// writes f32 out with ELU.
__global__ __launch_bounds__(256) void attn1_kernel(
        const _Float16* __restrict__ Wh, const float* __restrict__ s,
        const float* __restrict__ d, const unsigned short* __restrict__ nbr,
        const int* __restrict__ deg, float* __restrict__ out, int N) {
    __shared__ int nb[512];
    __shared__ float p[512];
    __shared__ float lred[1];
    __shared__ float red[4];
    const int t = threadIdx.x, lane = t & 63, row = blockIdx.x;
    const int M = deg[row];
    for (int j = t; j < M; j += 256) nb[j] = nbr[(size_t)row * 512 + j];
    __syncthreads();
    const float4* sp = (const float4*)(s + (size_t)row * 8);
    float4 s0 = sp[0], s1 = sp[1];
    const float sh = ((s0.x + s0.y) + (s0.z + s0.w)) + ((s1.x + s1.y) + (s1.z + s1.w));
    float lm = -INFINITY;
    for (int j = t; j < M; j += 256) {
        const float4* dp = (const float4*)(d + (size_t)nb[j] * 8);
        float4 d0 = dp[0], d1 = dp[1];
        float dv = ((d0.x + d0.y) + (d0.z + d0.w)) + ((d1.x + d1.y) + (d1.z + d1.w));
        float e = sh + dv;
        e = e > 0.f ? e : 0.2f * e;
        p[j] = e;
        lm = fmaxf(lm, e);
    }
    #pragma unroll
    for (int off = 32; off; off >>= 1) lm = fmaxf(lm, __shfl_xor(lm, off));
    if (lane == 0) red[t >> 6] = lm;
    __syncthreads();
    lm = fmaxf(fmaxf(red[0], red[1]), fmaxf(red[2], red[3]));
    float ls = 0.f;
    for (int j = t; j < M; j += 256) {
        float pe = expf(p[j] - lm);
        p[j] = pe;
        ls += pe;
    }
    #pragma unroll
    for (int off = 32; off; off >>= 1) ls += __shfl_xor(ls, off);
    __syncthreads();
    if (lane == 0) red[t >> 6] = ls;
    __syncthreads();
    ls = red[0] + red[1] + red[2] + red[3];
    if (t == 0) lred[0] = ls;
    __syncthreads();
    const int c = 2 * t;
    const float inv = 1.f / lred[0];
    const _Float16* base = Wh + c;
    float ax = 0.f, ay = 0.f;
    #pragma unroll 4
    for (int j = 0; j < M; ++j) {
        float pw = p[j];
        const f16x2 w = *(const f16x2*)(base + (size_t)nb[j] * 512);
        ax += pw * (float)w.x; ay += pw * (float)w.y;
    }
    ax *= inv; ay *= inv;
    ax = ax > 0.f ? ax : expm1f(ax);
    ay = ay > 0.f ? ay : expm1f(ay);
    float2 o; o.x = ax; o.y = ay;
    *(float2*)(out + (size_t)row * 512 + c) = o;
}

extern "C" void kernel_launch(void* const* d_in, const int* in_sizes, int n_in,
                              void* d_out, int out_size, void* d_ws, size_t ws_size,
                              hipStream_t stream) {
    const float* x   = (const float*)d_in[0];
    const float* adj = (const float*)d_in[2];
    const float* Ws  = (const float*)d_in[3];
    const float* a1  = (const float*)d_in[4];   // [H][64] flat, c = h*64+k
    const float* a2  = (const float*)d_in[5];
    const float* Wo  = (const float*)d_in[6];
    const float* ao1 = (const float*)d_in[7];   // [512]
    const float* ao2 = (const float*)d_in[8];
    float* out = (float*)d_out;
    const int N = GN;

    char* wsb = (char*)d_ws;
    _Float16* Whh  = (_Float16*)(wsb + 0);            // 4096*512 fp16 = 4 MiB
    _Float16* Whoh = (_Float16*)(wsb + 4194304);      // 4 MiB
    float* s_t   = (float*)(wsb + 8388608);           // 4096*8 f32
    float* d_t   = (float*)(wsb + 8519680);
    float* spart = (float*)(wsb + 8650752);
    float* dpart = (float*)(wsb + 8781824);
    unsigned short* nbrs = (unsigned short*)(wsb + 8912896);   // 4 MiB
    int*            deg  = (int*)(wsb + 13107200);             // 16 KiB
    unsigned short* xhi  = (unsigned short*)(wsb + 13123584);  // 4 MiB
    unsigned short* xlo  = (unsigned short*)(wsb + 17317888);  // 4 MiB
    unsigned short* hch  = (unsigned short*)(wsb + 21512192);  // 4 MiB
    unsigned short* hcl  = (unsigned short*)(wsb + 25706496);  // 4 MiB
    unsigned short* wshi = (unsigned short*)(wsb + 29900800);  // 512 KiB
    unsigned short* wslo = (unsigned short*)(wsb + 30425088);
    unsigned short* wohi = (unsigned short*)(wsb + 30949376);
    unsigned short* wolo = (unsigned short*)(wsb + 31473664);  // end ~32 MiB

    hipLaunchKernelGGL(prep, dim3(6272), dim3(256), 0, stream,
                       adj, Ws, Wo, x, nbrs, deg, wshi, wslo, wohi, wolo, xhi, xlo, N);
    hipLaunchKernelGGL(gemm_3t, dim3(512), dim3(256), 0, stream,
                       xhi, xlo, wshi, wslo, a1, a2, Whh, s_t, d_t, 4096, 512, 512);
    hipLaunchKernelGGL(attn8_kernel, dim3(4096), dim3(256), 0, stream,
                       Whh, s_t, d_t, nbrs, deg, hch, hcl, N);
    hipLaunchKernelGGL(gemm_3t, dim3(512), dim3(256), 0, stream,
                       hch, hcl, wohi, wolo, ao1, ao2, Whoh, spart, dpart, 4096, 512, 512);
    hipLaunchKernelGGL(attn1_kernel, dim3(4096), dim3(256), 0, stream,
                       Whoh, spart, dpart, nbrs, deg, out, N);
}